// Round 11
// baseline (563.370 us; speedup 1.0000x reference)
//
#include <hip/hip_runtime.h>
#include <hip/hip_bf16.h>

#define NN 50000     // nodes
#define NE 600000    // edges
#define NF 11        // raw features
#define DD 128       // hidden dim
#define NB 500       // graphs
#define MA 100       // max atoms per graph
#define NLAY 5       // conv layers
#define NBLK ((NN + 255) / 256)   // 196 scan blocks

typedef __attribute__((ext_vector_type(8))) short short8v;   // 8 bf16 (4 VGPR)
typedef __attribute__((ext_vector_type(4))) float float4v;

static __device__ __forceinline__ unsigned short f2bu(float f) {
    return __bfloat16_as_ushort(__float2bfloat16(f));
}

// --- zero an int region ----------------------------------------------------
__global__ __launch_bounds__(256) void k_zero(int* __restrict__ p, int n) {
    int i = blockIdx.x * 256 + threadIdx.x;
    if (i < n) p[i] = 0;
}

// --- W prep: transposed split bf16 (truncation hi + RNE lo) ----------------
__global__ __launch_bounds__(256) void k_wprep(const float* __restrict__ Ws,
                                               unsigned short* __restrict__ Wth,
                                               unsigned short* __restrict__ Wtl) {
    int idx = blockIdx.x * 256 + threadIdx.x;
    if (idx >= NLAY * DD * DD) return;
    int l   = idx / (DD * DD);
    int rem = idx - l * (DD * DD);
    int k   = rem >> 7, n = rem & 127;          // read coalesced in n
    float w = Ws[idx];
    unsigned hb = __float_as_uint(w) & 0xffff0000u;   // exact bf16 (truncate)
    float r = w - __uint_as_float(hb);                // exact in f32
    Wth[(size_t)l * DD * DD + n * DD + k] = (unsigned short)(hb >> 16);
    Wtl[(size_t)l * DD * DD + n * DD + k] = f2bu(r);
}

// --- expansion: x = log(atoms+1) @ W_exp + b_exp (f32 out) -----------------
__global__ __launch_bounds__(256) void k_expand(
        const float* __restrict__ atoms,
        const float* __restrict__ W_exp,
        const float* __restrict__ b_exp,
        float* __restrict__ x) {
    int sub  = threadIdx.x >> 7;            // 2 nodes per block
    int node = blockIdx.x * 2 + sub;
    int d    = threadIdx.x & 127;
    __shared__ float la[2][NF];
    if (node < NN && d < NF)
        la[sub][d] = logf(atoms[node * NF + d] + 1.0f);
    __syncthreads();
    if (node >= NN) return;
    float acc = b_exp[d];
#pragma unroll
    for (int f = 0; f < NF; ++f)
        acc = fmaf(la[sub][f], W_exp[f * DD + d], acc);
    x[(size_t)node * DD + d] = acc;
}

// --- degree count + per-graph count (fused) --------------------------------
__global__ __launch_bounds__(256) void k_count(const int* __restrict__ col,
                                               int* __restrict__ cnt,
                                               const int* __restrict__ batch,
                                               int* __restrict__ gcnt) {
    int i = blockIdx.x * 256 + threadIdx.x;
    if (i < NE) atomicAdd(cnt + col[i], 1);
    if (i < NN) atomicAdd(gcnt + batch[i], 1);
}

// --- scan1 + dinv/selfn (fused): block scans of cnt ------------------------
__global__ __launch_bounds__(256) void k_scan1(const int* __restrict__ cnt,
                                               int* __restrict__ ptrb,
                                               int* __restrict__ bsum,
                                               float* __restrict__ dinv,
                                               float* __restrict__ selfn) {
    __shared__ int s[256];
    int t = threadIdx.x;
    int i = blockIdx.x * 256 + t;
    int v = (i < NN) ? cnt[i] : 0;
    if (i < NN) {
        float r = 1.0f / sqrtf((float)v + 2.0f);
        dinv[i]  = r;
        selfn[i] = 2.0f * r * r;
    }
    s[t] = v;
    __syncthreads();
    for (int off = 1; off < 256; off <<= 1) {
        int tv = (t >= off) ? s[t - off] : 0;
        __syncthreads();
        s[t] += tv;
        __syncthreads();
    }
    if (i < NN) ptrb[i] = s[t] - v;
    if (t == 255) bsum[blockIdx.x] = s[255];
}

// --- scan2: bsum -> boff, then gcnt -> gptr (two 512-wide scans) -----------
__global__ __launch_bounds__(512) void k_scan2(const int* __restrict__ bsum,
                                               int* __restrict__ boff,
                                               int* __restrict__ ptr_last,
                                               const int* __restrict__ gcnt,
                                               int* __restrict__ gptr) {
    __shared__ int s[512];
    int t = threadIdx.x;
    // pass A: block sums
    int v = (t < NBLK) ? bsum[t] : 0;
    s[t] = v;
    __syncthreads();
    for (int off = 1; off < 512; off <<= 1) {
        int tv = (t >= off) ? s[t - off] : 0;
        __syncthreads();
        s[t] += tv;
        __syncthreads();
    }
    if (t < NBLK) boff[t] = s[t] - v;
    if (t == 511) *ptr_last = s[511];   // total == NE
    __syncthreads();
    // pass B: per-graph counts
    int v2 = (t < NB) ? gcnt[t] : 0;
    s[t] = v2;
    __syncthreads();
    for (int off = 1; off < 512; off <<= 1) {
        int tv = (t >= off) ? s[t - off] : 0;
        __syncthreads();
        s[t] += tv;
        __syncthreads();
    }
    if (t < NB) gptr[t] = s[t] - v2;
}

__global__ __launch_bounds__(256) void k_scan3(int* __restrict__ ptrb,
                                               const int* __restrict__ boff) {
    int i = blockIdx.x * 256 + threadIdx.x;
    if (i < NN) ptrb[i] += boff[blockIdx.x];
}

// --- scatter edges into CSR (sorted by target), packed (src, w) ------------
__global__ __launch_bounds__(256) void k_scatter(
        const int* __restrict__ conn, const int* __restrict__ ptrb,
        int* __restrict__ cursor, const float* __restrict__ dinv,
        int2* __restrict__ epack) {
    int e = blockIdx.x * 256 + threadIdx.x;
    if (e < NE) {
        int r = conn[e];
        int c = conn[NE + e];
        int p = ptrb[c] + atomicAdd(cursor + c, 1);
        int2 rec; rec.x = r; rec.y = __float_as_int(dinv[r] * dinv[c]);
        epack[p] = rec;
    }
}

// --- fused layer: relu( (P x) @ W + b ), f32 x, split-bf16 MFMA GEMM -------
// 16 nodes/block, 256 threads, LDS = 8KB (y split hi/lo, XOR-swizzled 16B).
// Phase 1: wave gathers 4 node-rows from f32 x; edge loop unrolled 8/4/1 for
//          deep MLP (8 ep + 8 x-row loads in flight). VGPR ~60 -> 8 waves/SIMD.
// Phase 2: 32x mfma_f32_16x16x32_bf16: (ah+al)(bh+bl), f32-accurate.
__global__ __launch_bounds__(256) void k_layer(
        const float* __restrict__ x, const int* __restrict__ ptrb,
        const int2* __restrict__ ep, const float* __restrict__ selfn,
        const unsigned short* __restrict__ Wth,
        const unsigned short* __restrict__ Wtl,
        const float* __restrict__ bias,
        float* __restrict__ xo,
        int last, const int* __restrict__ batch, const int* __restrict__ gptr,
        float* __restrict__ out) {
    __shared__ __align__(16) unsigned ylh[16 * 64];   // y_hi, swizzled
    __shared__ __align__(16) unsigned yll[16 * 64];   // y_lo, swizzled
    int tid  = threadIdx.x;
    int wave = tid >> 6, lane = tid & 63;
    int nodebase = blockIdx.x * 16;

    // phase 1: gather y rows (4 nodes per wave) from f32 x
    const float2* x2 = (const float2*)x;
#pragma unroll
    for (int i = 0; i < 4; ++i) {
        int row  = wave * 4 + i;
        int node = nodebase + row;
        int p0 = ptrb[node], p1 = ptrb[node + 1];
        float sn = selfn[node];
        float2 u = x2[(size_t)node * 64 + lane];
        float a0 = u.x * sn, a1 = u.y * sn;
        int p = p0;
        for (; p + 8 <= p1; p += 8) {
            int2 e0 = ep[p],     e1 = ep[p + 1], e2 = ep[p + 2], e3 = ep[p + 3];
            int2 e4 = ep[p + 4], e5 = ep[p + 5], e6 = ep[p + 6], e7 = ep[p + 7];
            float2 v0 = x2[(size_t)e0.x * 64 + lane];
            float2 v1 = x2[(size_t)e1.x * 64 + lane];
            float2 v2 = x2[(size_t)e2.x * 64 + lane];
            float2 v3 = x2[(size_t)e3.x * 64 + lane];
            float2 v4 = x2[(size_t)e4.x * 64 + lane];
            float2 v5 = x2[(size_t)e5.x * 64 + lane];
            float2 v6 = x2[(size_t)e6.x * 64 + lane];
            float2 v7 = x2[(size_t)e7.x * 64 + lane];
            a0 = fmaf(v0.x, __int_as_float(e0.y), a0); a1 = fmaf(v0.y, __int_as_float(e0.y), a1);
            a0 = fmaf(v1.x, __int_as_float(e1.y), a0); a1 = fmaf(v1.y, __int_as_float(e1.y), a1);
            a0 = fmaf(v2.x, __int_as_float(e2.y), a0); a1 = fmaf(v2.y, __int_as_float(e2.y), a1);
            a0 = fmaf(v3.x, __int_as_float(e3.y), a0); a1 = fmaf(v3.y, __int_as_float(e3.y), a1);
            a0 = fmaf(v4.x, __int_as_float(e4.y), a0); a1 = fmaf(v4.y, __int_as_float(e4.y), a1);
            a0 = fmaf(v5.x, __int_as_float(e5.y), a0); a1 = fmaf(v5.y, __int_as_float(e5.y), a1);
            a0 = fmaf(v6.x, __int_as_float(e6.y), a0); a1 = fmaf(v6.y, __int_as_float(e6.y), a1);
            a0 = fmaf(v7.x, __int_as_float(e7.y), a0); a1 = fmaf(v7.y, __int_as_float(e7.y), a1);
        }
        for (; p + 4 <= p1; p += 4) {
            int2 e0 = ep[p], e1 = ep[p + 1], e2 = ep[p + 2], e3 = ep[p + 3];
            float2 v0 = x2[(size_t)e0.x * 64 + lane];
            float2 v1 = x2[(size_t)e1.x * 64 + lane];
            float2 v2 = x2[(size_t)e2.x * 64 + lane];
            float2 v3 = x2[(size_t)e3.x * 64 + lane];
            a0 = fmaf(v0.x, __int_as_float(e0.y), a0); a1 = fmaf(v0.y, __int_as_float(e0.y), a1);
            a0 = fmaf(v1.x, __int_as_float(e1.y), a0); a1 = fmaf(v1.y, __int_as_float(e1.y), a1);
            a0 = fmaf(v2.x, __int_as_float(e2.y), a0); a1 = fmaf(v2.y, __int_as_float(e2.y), a1);
            a0 = fmaf(v3.x, __int_as_float(e3.y), a0); a1 = fmaf(v3.y, __int_as_float(e3.y), a1);
        }
        for (; p < p1; ++p) {
            int2 e = ep[p];
            float2 v = x2[(size_t)e.x * 64 + lane];
            float w = __int_as_float(e.y);
            a0 = fmaf(v.x, w, a0); a1 = fmaf(v.y, w, a1);
        }
        // exact truncation split: hi = top16 bits (exact), lo = RNE(residual)
        unsigned hb0 = __float_as_uint(a0) & 0xffff0000u;
        unsigned hb1 = __float_as_uint(a1) & 0xffff0000u;
        unsigned short l0 = f2bu(a0 - __uint_as_float(hb0));
        unsigned short l1 = f2bu(a1 - __uint_as_float(hb1));
        int widx = row * 64 + ((lane >> 2) ^ row) * 4 + (lane & 3);
        ylh[widx] = (hb0 >> 16) | (hb1 & 0xffff0000u);
        yll[widx] = (unsigned)l0 | ((unsigned)l1 << 16);
    }
    __syncthreads();

    // phase 2: 32x MFMA. A-frag row = lane&15, k0 = kb*32 + (lane>>4)*8.
    // B-frag col = wave*32 + nt*16 + (lane&15), same k0 (L2-hot global).
    float4v acc0 = {0.f, 0.f, 0.f, 0.f};
    float4v acc1 = {0.f, 0.f, 0.f, 0.f};
    const short8v* WTH8 = (const short8v*)Wth;
    const short8v* WTL8 = (const short8v*)Wtl;
    int arow = lane & 15;
    int n0c = wave * 32 + (lane & 15);        // nt=0 column
#pragma unroll
    for (int kb = 0; kb < 4; ++kb) {
        int chunk = (kb * 4 + (lane >> 4)) ^ arow;
        short8v ah = *(const short8v*)&ylh[arow * 64 + chunk * 4];
        short8v al = *(const short8v*)&yll[arow * 64 + chunk * 4];
        int bidx = kb * 4 + (lane >> 4);
        short8v bh0 = WTH8[n0c * 16 + bidx];
        short8v bl0 = WTL8[n0c * 16 + bidx];
        short8v bh1 = WTH8[(n0c + 16) * 16 + bidx];
        short8v bl1 = WTL8[(n0c + 16) * 16 + bidx];
        acc0 = __builtin_amdgcn_mfma_f32_16x16x32_bf16(ah, bh0, acc0, 0, 0, 0);
        acc0 = __builtin_amdgcn_mfma_f32_16x16x32_bf16(al, bh0, acc0, 0, 0, 0);
        acc0 = __builtin_amdgcn_mfma_f32_16x16x32_bf16(ah, bl0, acc0, 0, 0, 0);
        acc0 = __builtin_amdgcn_mfma_f32_16x16x32_bf16(al, bl0, acc0, 0, 0, 0);
        acc1 = __builtin_amdgcn_mfma_f32_16x16x32_bf16(ah, bh1, acc1, 0, 0, 0);
        acc1 = __builtin_amdgcn_mfma_f32_16x16x32_bf16(al, bh1, acc1, 0, 0, 0);
        acc1 = __builtin_amdgcn_mfma_f32_16x16x32_bf16(ah, bl1, acc1, 0, 0, 0);
        acc1 = __builtin_amdgcn_mfma_f32_16x16x32_bf16(al, bl1, acc1, 0, 0, 0);
    }

    // epilogue: D col = lane&15, row = (lane>>4)*4 + reg
#pragma unroll
    for (int nt = 0; nt < 2; ++nt) {
        int d  = wave * 32 + nt * 16 + (lane & 15);
        float bv = bias[d];
#pragma unroll
        for (int r = 0; r < 4; ++r) {
            int row  = (lane >> 4) * 4 + r;
            int node = nodebase + row;
            float o = fmaxf((nt ? acc1[r] : acc0[r]) + bv, 0.0f);
            if (!last) {
                xo[(size_t)node * DD + d] = o;
            } else {
                int b  = batch[node];
                int ix = b * MA + (node - gptr[b]);
                out[(size_t)ix * DD + d] = o;
            }
        }
    }
    if (last && wave == 0 && (lane & 15) == 0) {
#pragma unroll
        for (int r = 0; r < 4; ++r) {
            int node = nodebase + (lane >> 4) * 4 + r;
            int b  = batch[node];
            int ix = b * MA + (node - gptr[b]);
            out[(size_t)NB * MA * DD + ix] = 1.0f;   // mask True
        }
    }
}

extern "C" void kernel_launch(void* const* d_in, const int* in_sizes, int n_in,
                              void* d_out, int out_size, void* d_ws, size_t ws_size,
                              hipStream_t stream) {
    const float* atoms = (const float*)d_in[0];
    const int*   conn  = (const int*)d_in[1];
    const int*   batch = (const int*)d_in[2];
    const float* W_exp = (const float*)d_in[3];
    const float* b_exp = (const float*)d_in[4];
    const float* Ws    = (const float*)d_in[5];
    const float* bs    = (const float*)d_in[6];
    float* out = (float*)d_out;   // reference output dtype is float32

    char* ws = (char*)d_ws;
    size_t off = 0;
    auto nextbuf = [&](size_t bytes) {
        void* p = ws + off;
        off = (off + bytes + 255) & ~(size_t)255;
        return p;
    };
    float* x0 = (float*)nextbuf((size_t)NN * DD * 4);
    float* x1 = (float*)nextbuf((size_t)NN * DD * 4);
    unsigned short* Wth = (unsigned short*)nextbuf((size_t)NLAY * DD * DD * 2);
    unsigned short* Wtl = (unsigned short*)nextbuf((size_t)NLAY * DD * DD * 2);
    int*   izero = (int*)  nextbuf((size_t)(2 * NN + NB) * 4);  // cnt|cursor|gcnt
    int*   cnt    = izero;
    int*   cursor = izero + NN;
    int*   gcnt   = izero + 2 * NN;
    int*   ptrb  = (int*)  nextbuf((size_t)(NN + 1) * 4);
    float* dinv  = (float*)nextbuf((size_t)NN * 4);
    float* selfn = (float*)nextbuf((size_t)NN * 4);
    int2*  epack = (int2*) nextbuf((size_t)NE * 8);
    int*   gptr  = (int*)  nextbuf((size_t)NB * 4);
    int*   bsum  = (int*)  nextbuf((size_t)NBLK * 4);
    int*   boff  = (int*)  nextbuf((size_t)NBLK * 4);
    (void)ws_size; (void)n_in; (void)in_sizes; (void)out_size;

    const int NZ = 2 * NN + NB;
    k_zero   <<<(NZ + 255) / 256,    256, 0, stream>>>(izero, NZ);
    k_wprep  <<<(NLAY * DD * DD + 255) / 256, 256, 0, stream>>>(Ws, Wth, Wtl);
    k_expand <<<NN / 2,              256, 0, stream>>>(atoms, W_exp, b_exp, x0);
    k_count  <<<(NE + 255) / 256,    256, 0, stream>>>(conn + NE, cnt, batch, gcnt);
    k_scan1  <<<NBLK,                256, 0, stream>>>(cnt, ptrb, bsum, dinv, selfn);
    k_scan2  <<<1,                   512, 0, stream>>>(bsum, boff, ptrb + NN, gcnt, gptr);
    k_scan3  <<<NBLK,                256, 0, stream>>>(ptrb, boff);
    k_scatter<<<(NE + 255) / 256,    256, 0, stream>>>(conn, ptrb, cursor, dinv, epack);

    float* xa = x0;
    float* xc = x1;
    for (int l = 0; l < NLAY; ++l) {
        int last = (l == NLAY - 1);
        k_layer<<<NN / 16, 256, 0, stream>>>(xa, ptrb, epack, selfn,
                                             Wth + (size_t)l * DD * DD,
                                             Wtl + (size_t)l * DD * DD,
                                             bs + (size_t)l * DD,
                                             xc, last, batch, gptr, out);
        float* t = xa; xa = xc; xc = t;
    }
}

// Round 12
// 489.424 us; speedup vs baseline: 1.1511x; 1.1511x over previous
//
#include <hip/hip_runtime.h>
#include <hip/hip_bf16.h>

#define NN 50000     // nodes
#define NE 600000    // edges
#define NF 11        // raw features
#define DD 128       // hidden dim
#define NB 500       // graphs
#define MA 100       // max atoms per graph
#define NLAY 5       // conv layers
#define NBLK ((NN + 255) / 256)   // 196 scan blocks
#define LBLK ((NN + 31) / 32)     // 1563 layer blocks (last partial)

static __device__ __forceinline__ float bflo(unsigned u) {
    return __uint_as_float(u << 16);
}
static __device__ __forceinline__ float bfhi(unsigned u) {
    return __uint_as_float(u & 0xffff0000u);
}
static __device__ __forceinline__ unsigned short f2bu(float f) {
    return __bfloat16_as_ushort(__float2bfloat16(f));
}

// --- zero an int region ----------------------------------------------------
__global__ __launch_bounds__(256) void k_zero(int* __restrict__ p, int n) {
    int i = blockIdx.x * 256 + threadIdx.x;
    if (i < n) p[i] = 0;
}

// --- expansion: xb = bf16( log(atoms+1) @ W_exp + b_exp ) ------------------
__global__ __launch_bounds__(256) void k_expand(
        const float* __restrict__ atoms,
        const float* __restrict__ W_exp,
        const float* __restrict__ b_exp,
        __hip_bfloat16* __restrict__ xb) {
    int sub  = threadIdx.x >> 7;            // 2 nodes per block
    int node = blockIdx.x * 2 + sub;
    int d    = threadIdx.x & 127;
    __shared__ float la[2][NF];
    if (node < NN && d < NF)
        la[sub][d] = logf(atoms[node * NF + d] + 1.0f);
    __syncthreads();
    if (node >= NN) return;
    float acc = b_exp[d];
#pragma unroll
    for (int f = 0; f < NF; ++f)
        acc = fmaf(la[sub][f], W_exp[f * DD + d], acc);
    xb[(size_t)node * DD + d] = __float2bfloat16(acc);
}

// --- degree count + per-graph count (fused) --------------------------------
__global__ __launch_bounds__(256) void k_count(const int* __restrict__ col,
                                               int* __restrict__ cnt,
                                               const int* __restrict__ batch,
                                               int* __restrict__ gcnt) {
    int i = blockIdx.x * 256 + threadIdx.x;
    if (i < NE) atomicAdd(cnt + col[i], 1);
    if (i < NN) atomicAdd(gcnt + batch[i], 1);
}

// --- scan1 + dinv/selfn (fused): block scans of cnt ------------------------
__global__ __launch_bounds__(256) void k_scan1(const int* __restrict__ cnt,
                                               int* __restrict__ ptrb,
                                               int* __restrict__ bsum,
                                               float* __restrict__ dinv,
                                               float* __restrict__ selfn) {
    __shared__ int s[256];
    int t = threadIdx.x;
    int i = blockIdx.x * 256 + t;
    int v = (i < NN) ? cnt[i] : 0;
    if (i < NN) {
        float r = 1.0f / sqrtf((float)v + 2.0f);
        dinv[i]  = r;
        selfn[i] = 2.0f * r * r;
    }
    s[t] = v;
    __syncthreads();
    for (int off = 1; off < 256; off <<= 1) {
        int tv = (t >= off) ? s[t - off] : 0;
        __syncthreads();
        s[t] += tv;
        __syncthreads();
    }
    if (i < NN) ptrb[i] = s[t] - v;
    if (t == 255) bsum[blockIdx.x] = s[255];
}

// --- scan2: bsum -> boff, then gcnt -> gptr (two 512-wide scans) -----------
__global__ __launch_bounds__(512) void k_scan2(const int* __restrict__ bsum,
                                               int* __restrict__ boff,
                                               int* __restrict__ ptr_last,
                                               const int* __restrict__ gcnt,
                                               int* __restrict__ gptr) {
    __shared__ int s[512];
    int t = threadIdx.x;
    int v = (t < NBLK) ? bsum[t] : 0;
    s[t] = v;
    __syncthreads();
    for (int off = 1; off < 512; off <<= 1) {
        int tv = (t >= off) ? s[t - off] : 0;
        __syncthreads();
        s[t] += tv;
        __syncthreads();
    }
    if (t < NBLK) boff[t] = s[t] - v;
    if (t == 511) *ptr_last = s[511];   // total == NE
    __syncthreads();
    int v2 = (t < NB) ? gcnt[t] : 0;
    s[t] = v2;
    __syncthreads();
    for (int off = 1; off < 512; off <<= 1) {
        int tv = (t >= off) ? s[t - off] : 0;
        __syncthreads();
        s[t] += tv;
        __syncthreads();
    }
    if (t < NB) gptr[t] = s[t] - v2;
}

__global__ __launch_bounds__(256) void k_scan3(int* __restrict__ ptrb,
                                               const int* __restrict__ boff) {
    int i = blockIdx.x * 256 + threadIdx.x;
    if (i < NN) ptrb[i] += boff[blockIdx.x];
}

// --- scatter edges into CSR (sorted by target), packed (src, w) ------------
__global__ __launch_bounds__(256) void k_scatter(
        const int* __restrict__ conn, const int* __restrict__ ptrb,
        int* __restrict__ cursor, const float* __restrict__ dinv,
        int2* __restrict__ epack) {
    int e = blockIdx.x * 256 + threadIdx.x;
    if (e < NE) {
        int r = conn[e];
        int c = conn[NE + e];
        int p = ptrb[c] + atomicAdd(cursor + c, 1);
        int2 rec; rec.x = r; rec.y = __float_as_int(dinv[r] * dinv[c]);
        epack[p] = rec;
    }
}

// --- fused layer: relu( (P xb) @ W + b ), bf16 x, f32 VALU GEMM ------------
// 32 nodes/block, 256 threads, LDS = 16KB f32 y tile.
// Phase 1: wave gathers 8 node-rows (bf16 src 256B/row, f32 accum, unroll x4).
// Phase 2: thread = (colgroup dg of 4, node-sub np); 4 nodes/thread share each
//          W float4 read (global, L1/L2 broadcast); y reads are LDS
//          same-address broadcasts.
__global__ __launch_bounds__(256) void k_layer(
        const __hip_bfloat16* __restrict__ xb, const int* __restrict__ ptrb,
        const int2* __restrict__ ep, const float* __restrict__ selfn,
        const float* __restrict__ W, const float* __restrict__ bias,
        __hip_bfloat16* __restrict__ xob,
        int last, const int* __restrict__ batch, const int* __restrict__ gptr,
        float* __restrict__ out) {
    __shared__ float yt[32 * DD];   // 16 KB
    int tid  = threadIdx.x;
    int wave = tid >> 6, lane = tid & 63;
    int nodebase = blockIdx.x * 32;

    // phase 1: gather y rows (8 nodes per wave) from bf16 x
    const unsigned* xq = (const unsigned*)xb;   // 2 bf16 per word
#pragma unroll
    for (int i = 0; i < 8; ++i) {
        int row  = wave * 8 + i;
        int node = nodebase + row;
        float a0 = 0.0f, a1 = 0.0f;
        if (node < NN) {
            int p0 = ptrb[node], p1 = ptrb[node + 1];
            float sn = selfn[node];
            unsigned u = xq[(size_t)node * 64 + lane];
            a0 = bflo(u) * sn; a1 = bfhi(u) * sn;
            int p = p0;
            for (; p + 4 <= p1; p += 4) {
                int2 e0 = ep[p], e1 = ep[p + 1], e2 = ep[p + 2], e3 = ep[p + 3];
                unsigned v0 = xq[(size_t)e0.x * 64 + lane];
                unsigned v1 = xq[(size_t)e1.x * 64 + lane];
                unsigned v2 = xq[(size_t)e2.x * 64 + lane];
                unsigned v3 = xq[(size_t)e3.x * 64 + lane];
                float w0 = __int_as_float(e0.y), w1 = __int_as_float(e1.y);
                float w2 = __int_as_float(e2.y), w3 = __int_as_float(e3.y);
                a0 = fmaf(bflo(v0), w0, a0); a1 = fmaf(bfhi(v0), w0, a1);
                a0 = fmaf(bflo(v1), w1, a0); a1 = fmaf(bfhi(v1), w1, a1);
                a0 = fmaf(bflo(v2), w2, a0); a1 = fmaf(bfhi(v2), w2, a1);
                a0 = fmaf(bflo(v3), w3, a0); a1 = fmaf(bfhi(v3), w3, a1);
            }
            for (; p < p1; ++p) {
                int2 e = ep[p];
                unsigned v = xq[(size_t)e.x * 64 + lane];
                float w = __int_as_float(e.y);
                a0 = fmaf(bflo(v), w, a0); a1 = fmaf(bfhi(v), w, a1);
            }
        }
        float2 o; o.x = a0; o.y = a1;
        *(float2*)&yt[row * DD + lane * 2] = o;
    }
    __syncthreads();

    // phase 2: GEMM + bias + relu. thread covers 4 nodes x 4 cols.
    int dg = tid & 31;  int d0 = dg * 4;
    int np = tid >> 5;                     // 0..7
    const float4* W4 = (const float4*)W;
    float4 a0v = {0,0,0,0}, a1v = {0,0,0,0}, a2v = {0,0,0,0}, a3v = {0,0,0,0};
#pragma unroll 4
    for (int k = 0; k < DD; ++k) {
        float4 w4 = W4[k * 32 + dg];
        float y0 = yt[(np     ) * DD + k];
        float y1 = yt[(np +  8) * DD + k];
        float y2 = yt[(np + 16) * DD + k];
        float y3 = yt[(np + 24) * DD + k];
        a0v.x = fmaf(w4.x, y0, a0v.x); a0v.y = fmaf(w4.y, y0, a0v.y);
        a0v.z = fmaf(w4.z, y0, a0v.z); a0v.w = fmaf(w4.w, y0, a0v.w);
        a1v.x = fmaf(w4.x, y1, a1v.x); a1v.y = fmaf(w4.y, y1, a1v.y);
        a1v.z = fmaf(w4.z, y1, a1v.z); a1v.w = fmaf(w4.w, y1, a1v.w);
        a2v.x = fmaf(w4.x, y2, a2v.x); a2v.y = fmaf(w4.y, y2, a2v.y);
        a2v.z = fmaf(w4.z, y2, a2v.z); a2v.w = fmaf(w4.w, y2, a2v.w);
        a3v.x = fmaf(w4.x, y3, a3v.x); a3v.y = fmaf(w4.y, y3, a3v.y);
        a3v.z = fmaf(w4.z, y3, a3v.z); a3v.w = fmaf(w4.w, y3, a3v.w);
    }
    float4 bv = ((const float4*)bias)[dg];
    float4 accs[4] = {a0v, a1v, a2v, a3v};
#pragma unroll
    for (int nn = 0; nn < 4; ++nn) {
        int node = nodebase + np + nn * 8;
        if (node >= NN) continue;
        float ox = fmaxf(accs[nn].x + bv.x, 0.0f);
        float oy = fmaxf(accs[nn].y + bv.y, 0.0f);
        float oz = fmaxf(accs[nn].z + bv.z, 0.0f);
        float ow = fmaxf(accs[nn].w + bv.w, 0.0f);
        if (!last) {
            ushort4 pk;
            pk.x = f2bu(ox); pk.y = f2bu(oy); pk.z = f2bu(oz); pk.w = f2bu(ow);
            *(ushort4*)((unsigned short*)xob + (size_t)node * DD + d0) = pk;
        } else {
            int b  = batch[node];
            int ix = b * MA + (node - gptr[b]);
            float4 o4; o4.x = ox; o4.y = oy; o4.z = oz; o4.w = ow;
            *(float4*)&out[(size_t)ix * DD + d0] = o4;
        }
    }
    if (last && tid < 32) {
        int node = nodebase + tid;
        if (node < NN) {
            int b  = batch[node];
            int ix = b * MA + (node - gptr[b]);
            out[(size_t)NB * MA * DD + ix] = 1.0f;   // mask True
        }
    }
}

extern "C" void kernel_launch(void* const* d_in, const int* in_sizes, int n_in,
                              void* d_out, int out_size, void* d_ws, size_t ws_size,
                              hipStream_t stream) {
    const float* atoms = (const float*)d_in[0];
    const int*   conn  = (const int*)d_in[1];
    const int*   batch = (const int*)d_in[2];
    const float* W_exp = (const float*)d_in[3];
    const float* b_exp = (const float*)d_in[4];
    const float* Ws    = (const float*)d_in[5];
    const float* bs    = (const float*)d_in[6];
    float* out = (float*)d_out;   // reference output dtype is float32

    char* ws = (char*)d_ws;
    size_t off = 0;
    auto nextbuf = [&](size_t bytes) {
        void* p = ws + off;
        off = (off + bytes + 255) & ~(size_t)255;
        return p;
    };
    __hip_bfloat16* xb0 = (__hip_bfloat16*)nextbuf((size_t)NN * DD * 2);
    __hip_bfloat16* xb1 = (__hip_bfloat16*)nextbuf((size_t)NN * DD * 2);
    int*   izero = (int*)  nextbuf((size_t)(2 * NN + NB) * 4);  // cnt|cursor|gcnt
    int*   cnt    = izero;
    int*   cursor = izero + NN;
    int*   gcnt   = izero + 2 * NN;
    int*   ptrb  = (int*)  nextbuf((size_t)(NN + 1) * 4);
    float* dinv  = (float*)nextbuf((size_t)NN * 4);
    float* selfn = (float*)nextbuf((size_t)NN * 4);
    int2*  epack = (int2*) nextbuf((size_t)NE * 8);
    int*   gptr  = (int*)  nextbuf((size_t)NB * 4);
    int*   bsum  = (int*)  nextbuf((size_t)NBLK * 4);
    int*   boff  = (int*)  nextbuf((size_t)NBLK * 4);
    (void)ws_size; (void)n_in; (void)in_sizes; (void)out_size;

    const int NZ = 2 * NN + NB;
    k_zero   <<<(NZ + 255) / 256,    256, 0, stream>>>(izero, NZ);
    k_expand <<<NN / 2,              256, 0, stream>>>(atoms, W_exp, b_exp, xb0);
    k_count  <<<(NE + 255) / 256,    256, 0, stream>>>(conn + NE, cnt, batch, gcnt);
    k_scan1  <<<NBLK,                256, 0, stream>>>(cnt, ptrb, bsum, dinv, selfn);
    k_scan2  <<<1,                   512, 0, stream>>>(bsum, boff, ptrb + NN, gcnt, gptr);
    k_scan3  <<<NBLK,                256, 0, stream>>>(ptrb, boff);
    k_scatter<<<(NE + 255) / 256,    256, 0, stream>>>(conn, ptrb, cursor, dinv, epack);

    __hip_bfloat16* xa = xb0;
    __hip_bfloat16* xc = xb1;
    for (int l = 0; l < NLAY; ++l) {
        int last = (l == NLAY - 1);
        k_layer<<<LBLK, 256, 0, stream>>>(xa, ptrb, epack, selfn,
                                          Ws + (size_t)l * DD * DD,
                                          bs + (size_t)l * DD,
                                          xc, last, batch, gptr, out);
        __hip_bfloat16* t = xa; xa = xc; xc = t;
    }
}

// Round 13
// 487.293 us; speedup vs baseline: 1.1561x; 1.0044x over previous
//
#include <hip/hip_runtime.h>
#include <hip/hip_bf16.h>

#define NN 50000     // nodes
#define NE 600000    // edges
#define NF 11        // raw features
#define DD 128       // hidden dim
#define NB 500       // graphs
#define MA 100       // max atoms per graph
#define NLAY 5       // conv layers
#define NBLK ((NN + 255) / 256)   // 196 scan blocks
#define LBLK ((NN + 31) / 32)     // 1563 layer blocks (last partial)

static __device__ __forceinline__ float bflo(unsigned u) {
    return __uint_as_float(u << 16);
}
static __device__ __forceinline__ float bfhi(unsigned u) {
    return __uint_as_float(u & 0xffff0000u);
}
static __device__ __forceinline__ unsigned short f2bu(float f) {
    return __bfloat16_as_ushort(__float2bfloat16(f));
}

// --- zero an int region ----------------------------------------------------
__global__ __launch_bounds__(256) void k_zero(int* __restrict__ p, int n) {
    int i = blockIdx.x * 256 + threadIdx.x;
    if (i < n) p[i] = 0;
}

// --- fused: expand (bf16 x0) + degree count + graph count ------------------
// grid = NN/2 blocks (6.4M threads >= NE, NN).
__global__ __launch_bounds__(256) void k_pre(
        const float* __restrict__ atoms,
        const float* __restrict__ W_exp,
        const float* __restrict__ b_exp,
        __hip_bfloat16* __restrict__ xb,
        const int* __restrict__ conn,
        int* __restrict__ cnt,
        const int* __restrict__ batch,
        int* __restrict__ gcnt) {
    int gid = blockIdx.x * 256 + threadIdx.x;
    if (gid < NE) atomicAdd(cnt + conn[NE + gid], 1);
    if (gid < NN) atomicAdd(gcnt + batch[gid], 1);

    // expand: 2 nodes per block, 128 threads/node
    int sub  = threadIdx.x >> 7;
    int node = blockIdx.x * 2 + sub;
    int d    = threadIdx.x & 127;
    __shared__ float la[2][NF];
    if (d < NF)
        la[sub][d] = logf(atoms[node * NF + d] + 1.0f);
    __syncthreads();
    float acc = b_exp[d];
#pragma unroll
    for (int f = 0; f < NF; ++f)
        acc = fmaf(la[sub][f], W_exp[f * DD + d], acc);
    xb[(size_t)node * DD + d] = __float2bfloat16(acc);
}

// --- scan1 + dinv/selfn (fused): block-local scans of cnt ------------------
__global__ __launch_bounds__(256) void k_scan1(const int* __restrict__ cnt,
                                               int* __restrict__ ptrb,
                                               int* __restrict__ bsum,
                                               float* __restrict__ dinv,
                                               float* __restrict__ selfn) {
    __shared__ int s[256];
    int t = threadIdx.x;
    int i = blockIdx.x * 256 + t;
    int v = (i < NN) ? cnt[i] : 0;
    if (i < NN) {
        float r = 1.0f / sqrtf((float)v + 2.0f);
        dinv[i]  = r;
        selfn[i] = 2.0f * r * r;
    }
    s[t] = v;
    __syncthreads();
    for (int off = 1; off < 256; off <<= 1) {
        int tv = (t >= off) ? s[t - off] : 0;
        __syncthreads();
        s[t] += tv;
        __syncthreads();
    }
    if (i < NN) ptrb[i] = s[t] - v;   // block-local exclusive
    if (t == 255) bsum[blockIdx.x] = s[255];
}

// --- scan2: block offsets, ptrb finalize, graph ptr scan (1 block) ---------
__global__ __launch_bounds__(512) void k_scan2(const int* __restrict__ bsum,
                                               int* __restrict__ ptrb,
                                               const int* __restrict__ gcnt,
                                               int* __restrict__ gptr) {
    __shared__ int s[512];
    __shared__ int bo[512];
    int t = threadIdx.x;
    // pass A: scan of per-block sums -> bo (exclusive)
    int v = (t < NBLK) ? bsum[t] : 0;
    s[t] = v;
    __syncthreads();
    for (int off = 1; off < 512; off <<= 1) {
        int tv = (t >= off) ? s[t - off] : 0;
        __syncthreads();
        s[t] += tv;
        __syncthreads();
    }
    bo[t] = s[t] - v;
    if (t == 511) ptrb[NN] = s[511];   // total == NE
    __syncthreads();
    // pass B: per-graph counts -> gptr
    int v2 = (t < NB) ? gcnt[t] : 0;
    s[t] = v2;
    __syncthreads();
    for (int off = 1; off < 512; off <<= 1) {
        int tv = (t >= off) ? s[t - off] : 0;
        __syncthreads();
        s[t] += tv;
        __syncthreads();
    }
    if (t < NB) gptr[t] = s[t] - v2;
    // pass C: finalize ptrb (add block offsets)
    for (int i = t; i < NN; i += 512) ptrb[i] += bo[i >> 8];
}

// --- scatter edges into CSR (sorted by target), packed (src, w) ------------
__global__ __launch_bounds__(256) void k_scatter(
        const int* __restrict__ conn, const int* __restrict__ ptrb,
        int* __restrict__ cursor, const float* __restrict__ dinv,
        int2* __restrict__ epack) {
    int e = blockIdx.x * 256 + threadIdx.x;
    if (e < NE) {
        int r = conn[e];
        int c = conn[NE + e];
        int p = ptrb[c] + atomicAdd(cursor + c, 1);
        int2 rec; rec.x = r; rec.y = __float_as_int(dinv[r] * dinv[c]);
        epack[p] = rec;
    }
}

// --- fused layer: relu( (P xb) @ W + b ), bf16 x, f32 VALU GEMM ------------
// 32 nodes/block, 256 threads, LDS = 16KB f32 y tile.
// Phase 1 (dual-stream): each wave splits into two 32-lane halves; per
//   row-pair both halves issue unroll-4 edge loads concurrently -> up to
//   8 row-loads in flight per wave. Branchless tail via clamp+select
//   (wasted slots read x row 0, L1-hot, weight 0).
// Phase 2: thread = (colgroup of 4, node-sub); 4 nodes/thread share each
//   W float4 read; y reads are LDS broadcasts.
__global__ __launch_bounds__(256) void k_layer(
        const __hip_bfloat16* __restrict__ xb, const int* __restrict__ ptrb,
        const int2* __restrict__ ep, const float* __restrict__ selfn,
        const float* __restrict__ W, const float* __restrict__ bias,
        __hip_bfloat16* __restrict__ xob,
        int last, const int* __restrict__ batch, const int* __restrict__ gptr,
        float* __restrict__ out) {
    __shared__ float yt[32 * DD];   // 16 KB
    int tid  = threadIdx.x;
    int wave = tid >> 6, lane = tid & 63;
    int half = lane >> 5, sub = lane & 31;
    int nodebase = blockIdx.x * 32;

    const uint2* xq2 = (const uint2*)xb;   // 4 bf16 per 8B

    // phase 1: 4 row-pairs per wave; this lane works row = pairbase + half
#pragma unroll
    for (int j = 0; j < 4; ++j) {
        int row  = wave * 8 + j * 2 + half;
        int node = nodebase + row;
        float a0 = 0.f, a1 = 0.f, a2 = 0.f, a3 = 0.f;
        int p0 = 0, deg = 0;
        if (node < NN) {
            p0 = ptrb[node];
            deg = ptrb[node + 1] - p0;
            float sn = selfn[node];
            uint2 u = xq2[(size_t)node * 32 + sub];
            a0 = bflo(u.x) * sn; a1 = bfhi(u.x) * sn;
            a2 = bflo(u.y) * sn; a3 = bfhi(u.y) * sn;
        }
        int dother = __shfl_xor(deg, 32);
        int dmax = max(deg, dother);
        int dcl = max(deg - 1, 0);
        for (int k = 0; k < dmax; k += 4) {
            int o0 = min(k + 0, dcl), o1 = min(k + 1, dcl);
            int o2 = min(k + 2, dcl), o3 = min(k + 3, dcl);
            int2 e0 = ep[p0 + o0];
            int2 e1 = ep[p0 + o1];
            int2 e2 = ep[p0 + o2];
            int2 e3 = ep[p0 + o3];
            bool v0 = (k + 0) < deg, v1 = (k + 1) < deg;
            bool v2 = (k + 2) < deg, v3 = (k + 3) < deg;
            int s0 = v0 ? e0.x : 0, s1 = v1 ? e1.x : 0;
            int s2 = v2 ? e2.x : 0, s3 = v3 ? e3.x : 0;
            float w0 = v0 ? __int_as_float(e0.y) : 0.f;
            float w1 = v1 ? __int_as_float(e1.y) : 0.f;
            float w2 = v2 ? __int_as_float(e2.y) : 0.f;
            float w3 = v3 ? __int_as_float(e3.y) : 0.f;
            uint2 q0 = xq2[(size_t)s0 * 32 + sub];
            uint2 q1 = xq2[(size_t)s1 * 32 + sub];
            uint2 q2 = xq2[(size_t)s2 * 32 + sub];
            uint2 q3 = xq2[(size_t)s3 * 32 + sub];
            a0 = fmaf(bflo(q0.x), w0, a0); a1 = fmaf(bfhi(q0.x), w0, a1);
            a2 = fmaf(bflo(q0.y), w0, a2); a3 = fmaf(bfhi(q0.y), w0, a3);
            a0 = fmaf(bflo(q1.x), w1, a0); a1 = fmaf(bfhi(q1.x), w1, a1);
            a2 = fmaf(bflo(q1.y), w1, a2); a3 = fmaf(bfhi(q1.y), w1, a3);
            a0 = fmaf(bflo(q2.x), w2, a0); a1 = fmaf(bfhi(q2.x), w2, a1);
            a2 = fmaf(bflo(q2.y), w2, a2); a3 = fmaf(bfhi(q2.y), w2, a3);
            a0 = fmaf(bflo(q3.x), w3, a0); a1 = fmaf(bfhi(q3.x), w3, a1);
            a2 = fmaf(bflo(q3.y), w3, a2); a3 = fmaf(bfhi(q3.y), w3, a3);
        }
        float4 o; o.x = a0; o.y = a1; o.z = a2; o.w = a3;
        *(float4*)&yt[row * DD + sub * 4] = o;
    }
    __syncthreads();

    // phase 2: GEMM + bias + relu. thread covers 4 nodes x 4 cols.
    int dg = tid & 31;  int d0 = dg * 4;
    int np = tid >> 5;                     // 0..7
    const float4* W4 = (const float4*)W;
    float4 a0v = {0,0,0,0}, a1v = {0,0,0,0}, a2v = {0,0,0,0}, a3v = {0,0,0,0};
#pragma unroll 4
    for (int k = 0; k < DD; ++k) {
        float4 w4 = W4[k * 32 + dg];
        float y0 = yt[(np     ) * DD + k];
        float y1 = yt[(np +  8) * DD + k];
        float y2 = yt[(np + 16) * DD + k];
        float y3 = yt[(np + 24) * DD + k];
        a0v.x = fmaf(w4.x, y0, a0v.x); a0v.y = fmaf(w4.y, y0, a0v.y);
        a0v.z = fmaf(w4.z, y0, a0v.z); a0v.w = fmaf(w4.w, y0, a0v.w);
        a1v.x = fmaf(w4.x, y1, a1v.x); a1v.y = fmaf(w4.y, y1, a1v.y);
        a1v.z = fmaf(w4.z, y1, a1v.z); a1v.w = fmaf(w4.w, y1, a1v.w);
        a2v.x = fmaf(w4.x, y2, a2v.x); a2v.y = fmaf(w4.y, y2, a2v.y);
        a2v.z = fmaf(w4.z, y2, a2v.z); a2v.w = fmaf(w4.w, y2, a2v.w);
        a3v.x = fmaf(w4.x, y3, a3v.x); a3v.y = fmaf(w4.y, y3, a3v.y);
        a3v.z = fmaf(w4.z, y3, a3v.z); a3v.w = fmaf(w4.w, y3, a3v.w);
    }
    float4 bv = ((const float4*)bias)[dg];
    float4 accs[4] = {a0v, a1v, a2v, a3v};
#pragma unroll
    for (int nn = 0; nn < 4; ++nn) {
        int node = nodebase + np + nn * 8;
        if (node >= NN) continue;
        float ox = fmaxf(accs[nn].x + bv.x, 0.0f);
        float oy = fmaxf(accs[nn].y + bv.y, 0.0f);
        float oz = fmaxf(accs[nn].z + bv.z, 0.0f);
        float ow = fmaxf(accs[nn].w + bv.w, 0.0f);
        if (!last) {
            ushort4 pk;
            pk.x = f2bu(ox); pk.y = f2bu(oy); pk.z = f2bu(oz); pk.w = f2bu(ow);
            *(ushort4*)((unsigned short*)xob + (size_t)node * DD + d0) = pk;
        } else {
            int b  = batch[node];
            int ix = b * MA + (node - gptr[b]);
            float4 o4; o4.x = ox; o4.y = oy; o4.z = oz; o4.w = ow;
            *(float4*)&out[(size_t)ix * DD + d0] = o4;
        }
    }
    if (last && tid < 32) {
        int node = nodebase + tid;
        if (node < NN) {
            int b  = batch[node];
            int ix = b * MA + (node - gptr[b]);
            out[(size_t)NB * MA * DD + ix] = 1.0f;   // mask True
        }
    }
}

extern "C" void kernel_launch(void* const* d_in, const int* in_sizes, int n_in,
                              void* d_out, int out_size, void* d_ws, size_t ws_size,
                              hipStream_t stream) {
    const float* atoms = (const float*)d_in[0];
    const int*   conn  = (const int*)d_in[1];
    const int*   batch = (const int*)d_in[2];
    const float* W_exp = (const float*)d_in[3];
    const float* b_exp = (const float*)d_in[4];
    const float* Ws    = (const float*)d_in[5];
    const float* bs    = (const float*)d_in[6];
    float* out = (float*)d_out;   // reference output dtype is float32

    char* ws = (char*)d_ws;
    size_t off = 0;
    auto nextbuf = [&](size_t bytes) {
        void* p = ws + off;
        off = (off + bytes + 255) & ~(size_t)255;
        return p;
    };
    __hip_bfloat16* xb0 = (__hip_bfloat16*)nextbuf((size_t)NN * DD * 2);
    __hip_bfloat16* xb1 = (__hip_bfloat16*)nextbuf((size_t)NN * DD * 2);
    int*   izero = (int*)  nextbuf((size_t)(2 * NN + NB) * 4);  // cnt|cursor|gcnt
    int*   cnt    = izero;
    int*   cursor = izero + NN;
    int*   gcnt   = izero + 2 * NN;
    int*   ptrb  = (int*)  nextbuf((size_t)(NN + 1) * 4);
    float* dinv  = (float*)nextbuf((size_t)NN * 4);
    float* selfn = (float*)nextbuf((size_t)NN * 4);
    int2*  epack = (int2*) nextbuf((size_t)(NE + 8) * 8);   // +pad for clamped reads
    int*   gptr  = (int*)  nextbuf((size_t)NB * 4);
    int*   bsum  = (int*)  nextbuf((size_t)NBLK * 4);
    (void)ws_size; (void)n_in; (void)in_sizes; (void)out_size;

    const int NZ = 2 * NN + NB;
    k_zero   <<<(NZ + 255) / 256,    256, 0, stream>>>(izero, NZ);
    k_pre    <<<NN / 2,              256, 0, stream>>>(atoms, W_exp, b_exp, xb0,
                                                       conn, cnt, batch, gcnt);
    k_scan1  <<<NBLK,                256, 0, stream>>>(cnt, ptrb, bsum, dinv, selfn);
    k_scan2  <<<1,                   512, 0, stream>>>(bsum, ptrb, gcnt, gptr);
    k_scatter<<<(NE + 255) / 256,    256, 0, stream>>>(conn, ptrb, cursor, dinv, epack);

    __hip_bfloat16* xa = xb0;
    __hip_bfloat16* xc = xb1;
    for (int l = 0; l < NLAY; ++l) {
        int last = (l == NLAY - 1);
        k_layer<<<LBLK, 256, 0, stream>>>(xa, ptrb, epack, selfn,
                                          Ws + (size_t)l * DD * DD,
                                          bs + (size_t)l * DD,
                                          xc, last, batch, gptr, out);
        __hip_bfloat16* t = xa; xa = xc; xc = t;
    }
}